// Round 16
// baseline (368.583 us; speedup 1.0000x reference)
//
#include <hip/hip_runtime.h>
#include <math.h>

#define S_DIM 1024
#define R_DIM 256
#define C_DIM 256
#define SCALE 0.17677669529663687f  // 1/sqrt(32)

typedef short bf16x8 __attribute__((ext_vector_type(8)));
typedef float f32x4 __attribute__((ext_vector_type(4)));

__device__ __forceinline__ float wred(float v) {
#pragma unroll
  for (int m = 32; m >= 1; m >>= 1) v += __shfl_xor(v, m, 64);
  return v;
}

__device__ __forceinline__ short f2bf(float f) {
  union { float f; unsigned u; } v;
  v.f = f;
  unsigned r = v.u + 0x7fffu + ((v.u >> 16) & 1u);  // RNE
  return (short)(r >> 16);
}

__device__ __forceinline__ float bf2f(short s) {
  union { unsigned u; float f; } v;
  v.u = ((unsigned)(unsigned short)s) << 16;
  return v.f;
}

__device__ __forceinline__ float fast_sigmoid_mul(float o, float gl) {
  return o * __builtin_amdgcn_rcpf(1.f + __expf(-gl));
}

// ---------------- K0: pre-swizzle weights into B-fragment bf16 layouts ----
__global__ __launch_bounds__(256)
void k0_prep(const float* __restrict__ w_g, const float* __restrict__ w_o,
             const float* __restrict__ w_k, const float* __restrict__ w_v,
             short* __restrict__ wgB, short* __restrict__ woB,
             short* __restrict__ wkvB) {
  const int id = blockIdx.x * 256 + threadIdx.x;  // 18432 ids
  if (id < 16384) {
    const int which = id >> 13;
    const int s = id & 8191;
    const int n = s & 255, g = (s >> 8) & 3, kb = s >> 10;
    const float* W = which ? w_o : w_g;
    short* Out = which ? woB : wgB;
#pragma unroll
    for (int j = 0; j < 8; ++j)
      Out[(((size_t)kb * 256 + n) * 4 + g) * 8 + j] =
          f2bf(W[(size_t)(kb * 32 + g * 8 + j) * 256 + n]);
  } else {
    const int s = id - 16384;  // 0..2047
    const int n = s & 63, g = (s >> 6) & 3, kb = s >> 8;
    const float* W = (n < 32) ? w_k : w_v;
    const int nn = n & 31;
#pragma unroll
    for (int j = 0; j < 8; ++j)
      wkvB[(((size_t)kb * 64 + n) * 4 + g) * 8 + j] =
          f2bf(W[(size_t)(kb * 32 + g * 8 + j) * 32 + nn]);
  }
}

// ---------------- K1: LN -> bf16 frag LDS -> MFMA K/V(bf16,T) + pool ------
// K/V stored bf16 transposed: Kt/Vt[r][s][32]
__global__ __launch_bounds__(256, 4)
void k1_ln_kv(const float* __restrict__ mIn, const float* __restrict__ ln_g,
              const float* __restrict__ ln_b, const short* __restrict__ wkvB,
              const int* __restrict__ mask,
              float* __restrict__ mu_ws, float* __restrict__ rs_ws,
              short* __restrict__ Kt, short* __restrict__ Vt,
              float* __restrict__ pool_ws) {
  __shared__ __align__(16) short A_lds[2048 * 8];  // 32 KB, frag-ordered X
  __shared__ float mask_s[64];
  __shared__ float4 poolp[4][64];                  // 4 KB
  const int r  = blockIdx.y;
  const int s0 = blockIdx.x * 64;
  const int t  = threadIdx.x;

  if (t < 64) mask_s[t] = mask[(s0 + t) * R_DIM + r] ? 1.f : 0.f;

  // ---- pass 1: LN stats (4-lane reduce) + bf16 frag write ----
  {
    const int rw = t >> 2;  // row 0..63
    const int q  = t & 3;   // col quarter
    const size_t p = (size_t)(s0 + rw) * R_DIM + r;
    const float* src = mIn + p * C_DIM + q * 64;
    float4 xv[16];
    float sum = 0.f, ssq = 0.f;
#pragma unroll
    for (int i = 0; i < 16; ++i) {
      xv[i] = *(const float4*)(src + i * 4);
      sum += xv[i].x + xv[i].y + xv[i].z + xv[i].w;
      ssq += xv[i].x * xv[i].x + xv[i].y * xv[i].y + xv[i].z * xv[i].z +
             xv[i].w * xv[i].w;
    }
    sum += __shfl_xor(sum, 1, 64); ssq += __shfl_xor(ssq, 1, 64);
    sum += __shfl_xor(sum, 2, 64); ssq += __shfl_xor(ssq, 2, 64);
    const float mu = sum * (1.f / 256.f);
    const float var = ssq * (1.f / 256.f) - mu * mu;
    const float rs = rsqrtf(var + 1e-5f);
    if (q == 0) { mu_ws[p] = mu; rs_ws[p] = rs; }

    const int gw = rw >> 4;
    const int lf0 = rw & 15;
#pragma unroll
    for (int kh = 0; kh < 2; ++kh) {
      const int kb = 2 * q + kh;
#pragma unroll
      for (int g = 0; g < 4; ++g) {
        const int lidx = kh * 32 + g * 8;
        const float4 a0 = xv[lidx >> 2], a1 = xv[(lidx >> 2) + 1];
        const float4 g0 = *(const float4*)(ln_g + kb * 32 + g * 8);
        const float4 g1 = *(const float4*)(ln_g + kb * 32 + g * 8 + 4);
        const float4 b0 = *(const float4*)(ln_b + kb * 32 + g * 8);
        const float4 b1 = *(const float4*)(ln_b + kb * 32 + g * 8 + 4);
        bf16x8 f;
        f[0] = f2bf((a0.x - mu) * rs * g0.x + b0.x);
        f[1] = f2bf((a0.y - mu) * rs * g0.y + b0.y);
        f[2] = f2bf((a0.z - mu) * rs * g0.z + b0.z);
        f[3] = f2bf((a0.w - mu) * rs * g0.w + b0.w);
        f[4] = f2bf((a1.x - mu) * rs * g1.x + b1.x);
        f[5] = f2bf((a1.y - mu) * rs * g1.y + b1.y);
        f[6] = f2bf((a1.z - mu) * rs * g1.z + b1.z);
        f[7] = f2bf((a1.w - mu) * rs * g1.w + b1.w);
        int byte = (((gw * 8 + kb) * 64 + lf0 + g * 16) << 4) ^ (((kb >> 1) & 3) << 5);
        *(bf16x8*)((char*)A_lds + byte) = f;
      }
    }
  }
  __syncthreads();

  // ---- MFMA: [16 rows/wave] x [64 cols K|V] x 256; store bf16 transposed --
  {
    const int w = t >> 6, l = t & 63;
    const int lm = l & 15, g = l >> 4;
    f32x4 acc[4];
#pragma unroll
    for (int ni = 0; ni < 4; ++ni) acc[ni] = (f32x4){0.f, 0.f, 0.f, 0.f};
#pragma unroll
    for (int kb = 0; kb < 8; ++kb) {
      const int byte = (((w * 8 + kb) * 64 + l) << 4) ^ (((kb >> 1) & 3) << 5);
      const bf16x8 a = *(const bf16x8*)((char*)A_lds + byte);
      bf16x8 bfr[4];
#pragma unroll
      for (int ni = 0; ni < 4; ++ni)
        bfr[ni] = *(const bf16x8*)(wkvB + (((size_t)kb * 64 + lm + ni * 16) * 4 + g) * 8);
#pragma unroll
      for (int ni = 0; ni < 4; ++ni)
        acc[ni] = __builtin_amdgcn_mfma_f32_16x16x32_bf16(a, bfr[ni], acc[ni], 0, 0, 0);
    }
#pragma unroll
    for (int ni = 0; ni < 4; ++ni) {
      const int col = lm + ni * 16;
      short* Out = (col < 32) ? Kt : Vt;
      const int cc = col & 31;
#pragma unroll
      for (int reg = 0; reg < 4; ++reg) {
        const int s = s0 + w * 16 + g * 4 + reg;
        Out[((size_t)r * 1024 + s) * 32 + cc] = f2bf(acc[ni][reg]);
      }
    }
  }

  // ---- pool: masked column sums from frag LDS (rotated rows) ----
  {
    const int lc = t & 63;
    const int wq = t >> 6;
    const int kb = lc >> 3, g2 = (lc >> 1) & 3, bh = (lc & 1) * 4;
    float4 ps = make_float4(0.f, 0.f, 0.f, 0.f);
    for (int i = 0; i < 16; ++i) {
      const int rloc = (i + lc) & 15;
      const int byte =
          ((((wq * 8 + kb) * 64 + rloc + g2 * 16) << 4) + bh * 2) ^ (((kb >> 1) & 3) << 5);
      const short4 xb = *(const short4*)((char*)A_lds + byte);
      const float mk = mask_s[wq * 16 + rloc];
      ps.x += mk * bf2f(xb.x);
      ps.y += mk * bf2f(xb.y);
      ps.z += mk * bf2f(xb.z);
      ps.w += mk * bf2f(xb.w);
    }
    poolp[wq][lc] = ps;
  }
  __syncthreads();
  if (t < 64) {
    const float4 a = poolp[0][t], b = poolp[1][t], c = poolp[2][t], d = poolp[3][t];
    atomicAdd(&pool_ws[r * C_DIM + t * 4 + 0], a.x + b.x + c.x + d.x);
    atomicAdd(&pool_ws[r * C_DIM + t * 4 + 1], a.y + b.y + c.y + d.y);
    atomicAdd(&pool_ws[r * C_DIM + t * 4 + 2], a.z + b.z + c.z + d.z);
    atomicAdd(&pool_ws[r * C_DIM + t * 4 + 3], a.w + b.w + c.w + d.w);
  }
}

// ---------------- K2: finalize pool, compute Q -----------------------------
__global__ __launch_bounds__(256, 2)
void k2_q(const float* __restrict__ pool_ws, const int* __restrict__ mask,
          const float* __restrict__ w_q, float* __restrict__ Q_ws) {
  __shared__ float qp[256];
  __shared__ float wsum[4];
  const int r = blockIdx.x, t = threadIdx.x;
  int cnt = 0;
  for (int s = t; s < S_DIM; s += 256) cnt += mask[s * R_DIM + r];
  float cf = wred((float)cnt);
  if ((t & 63) == 0) wsum[t >> 6] = cf;
  __syncthreads();
  const float denom = wsum[0] + wsum[1] + wsum[2] + wsum[3] + 1e-10f;
  qp[t] = pool_ws[r * C_DIM + t] / denom;
  __syncthreads();
  float acc = 0.f;
  for (int c = 0; c < 256; ++c) acc += qp[c] * w_q[c * 256 + t];
  Q_ws[r * 256 + t] = acc * SCALE;
}

// ---------------- K3eb: fused E=exp(QK) -> N_part, D_part -----------------
// grid (4, 256): block = 256-s chunk at one r. No E round-trip to HBM.
__global__ __launch_bounds__(256, 4)
void k3eb(const short* __restrict__ Kt, const short* __restrict__ Vt,
          const float* __restrict__ Q_ws, const int* __restrict__ mask,
          float* __restrict__ Npart, float* __restrict__ D_ws) {
  __shared__ float q[256];
  __shared__ float A_s[8 * 256];                   // 8 KB
  __shared__ __align__(16) short V_s[256 * 32];    // 16 KB
  const int ch = blockIdx.x, r = blockIdx.y;
  const int t = threadIdx.x;
  const int sb = ch * 256;

  q[t] = Q_ws[r * 256 + t];
  // stage V chunk (16 KB contiguous, linear)
  {
    const short* vp = Vt + ((size_t)r * 1024 + sb) * 32;
#pragma unroll
    for (int i = 0; i < 4; ++i) {
      const int u = i * 256 + t;
      *(bf16x8*)(V_s + u * 8) = *(const bf16x8*)(vp + u * 8);
    }
  }
  // K row for this thread's s
  const int s = sb + t;
  const short* kp = Kt + ((size_t)r * 1024 + s) * 32;
  bf16x8 kr[4];
#pragma unroll
  for (int i = 0; i < 4; ++i) kr[i] = *(const bf16x8*)(kp + i * 8);
  const int mk = mask[s * R_DIM + r];
  __syncthreads();

  float kf[32];
#pragma unroll
  for (int i = 0; i < 4; ++i)
#pragma unroll
    for (int j = 0; j < 8; ++j) kf[i * 8 + j] = bf2f(kr[i][j]);
#pragma unroll
  for (int h = 0; h < 8; ++h) {
    float a = 0.f;
#pragma unroll
    for (int d = 0; d < 32; ++d) a += q[h * 32 + d] * kf[d];
    A_s[h * 256 + t] = mk ? __expf(a) : 0.f;
  }
  __syncthreads();

  const int h = t >> 5, d = t & 31;
  const float* ap = A_s + h * 256;
  float o = 0.f;
  for (int s4 = 0; s4 < 256; s4 += 4) {
    const float4 a4 = *(const float4*)(ap + s4);
    o += a4.x * bf2f(V_s[(s4 + 0) * 32 + d]);
    o += a4.y * bf2f(V_s[(s4 + 1) * 32 + d]);
    o += a4.z * bf2f(V_s[(s4 + 2) * 32 + d]);
    o += a4.w * bf2f(V_s[(s4 + 3) * 32 + d]);
  }
  Npart[(size_t)ch * 65536 + r * 256 + t] = o;
  // D partial: strided sum within 32-lane d-group (xor<=16 stays in-group)
  float ds = 0.f;
  for (int s1 = d; s1 < 256; s1 += 32) ds += ap[s1];
#pragma unroll
  for (int mkk = 16; mkk >= 1; mkk >>= 1) ds += __shfl_xor(ds, mkk, 64);
  if (d == 0) atomicAdd(&D_ws[r * 8 + h], ds);
}

// ---------------- K3c: O_T[c][r] = (sum_ch N) / D (transposed for k4) -----
__global__ __launch_bounds__(256)
void k3c_norm(const float* __restrict__ Npart, const float* __restrict__ D_ws,
              float* __restrict__ O_T) {
  const int r = blockIdx.x, t = threadIdx.x;
  const int idx = r * 256 + t;
  const float n = Npart[idx] + Npart[65536 + idx] + Npart[131072 + idx] +
                  Npart[196608 + idx];
  O_T[t * 256 + r] = n / (D_ws[r * 8 + (t >> 5)] + 1e-30f);
}

// ---------------- K4: recompute X -> gate GEMM -> sigmoid*O -> out GEMM ----
// (R6/R13 champion + O^T float4 gather in the scatter phase)
__global__ __launch_bounds__(256, 4)
void k4_mfma(const float* __restrict__ mIn, const float* __restrict__ ln_g,
             const float* __restrict__ ln_b, const float* __restrict__ mu_ws,
             const float* __restrict__ rs_ws, const short* __restrict__ wgB,
             const float* __restrict__ b_g, const float* __restrict__ O_T,
             const short* __restrict__ woB, const float* __restrict__ b_o,
             float* __restrict__ out) {
  __shared__ __align__(16) short A_lds[2048 * 8];  // 32 KB
  const int t = threadIdx.x;
  const int p0 = blockIdx.x * 64;
  const int r0 = p0 & 255;
  const int l = t & 63;
  const int w = t >> 6;
  const int lm = l & 15;
  const int g = l >> 4;

  {
    const int row = w * 16 + lm;
    const size_t p = (size_t)(p0 + row);
    const float mu = mu_ws[p], rs = rs_ws[p];
    const float* mrow = mIn + p * 256 + g * 8;
    const float* gp = ln_g + g * 8;
    const float* bp = ln_b + g * 8;
#pragma unroll
    for (int kb = 0; kb < 8; ++kb) {
      const float4 m0 = *(const float4*)(mrow + kb * 32);
      const float4 m1 = *(const float4*)(mrow + kb * 32 + 4);
      const float4 g0 = *(const float4*)(gp + kb * 32);
      const float4 g1 = *(const float4*)(gp + kb * 32 + 4);
      const float4 b0 = *(const float4*)(bp + kb * 32);
      const float4 b1 = *(const float4*)(bp + kb * 32 + 4);
      bf16x8 xf;
      xf[0] = f2bf((m0.x - mu) * rs * g0.x + b0.x);
      xf[1] = f2bf((m0.y - mu) * rs * g0.y + b0.y);
      xf[2] = f2bf((m0.z - mu) * rs * g0.z + b0.z);
      xf[3] = f2bf((m0.w - mu) * rs * g0.w + b0.w);
      xf[4] = f2bf((m1.x - mu) * rs * g1.x + b1.x);
      xf[5] = f2bf((m1.y - mu) * rs * g1.y + b1.y);
      xf[6] = f2bf((m1.z - mu) * rs * g1.z + b1.z);
      xf[7] = f2bf((m1.w - mu) * rs * g1.w + b1.w);
      *(bf16x8*)(A_lds + ((w * 8 + kb) * 64 + l) * 8) = xf;
    }
  }
  __syncthreads();

  const int col = w * 64 + lm;
  f32x4 acc[4][4];

#pragma unroll
  for (int ni = 0; ni < 4; ++ni) {
    const float bg = b_g[col + ni * 16];
#pragma unroll
    for (int mi = 0; mi < 4; ++mi) acc[mi][ni] = (f32x4){bg, bg, bg, bg};
  }
#pragma unroll
  for (int kb = 0; kb < 8; ++kb) {
    bf16x8 a[4], bb[4];
#pragma unroll
    for (int mi = 0; mi < 4; ++mi)
      a[mi] = *(const bf16x8*)(A_lds + ((mi * 8 + kb) * 64 + l) * 8);
#pragma unroll
    for (int ni = 0; ni < 4; ++ni)
      bb[ni] = *(const bf16x8*)(wgB + (((size_t)kb * 256 + col + ni * 16) * 4 + g) * 8);
#pragma unroll
    for (int mi = 0; mi < 4; ++mi)
#pragma unroll
      for (int ni = 0; ni < 4; ++ni)
        acc[mi][ni] = __builtin_amdgcn_mfma_f32_16x16x32_bf16(a[mi], bb[ni], acc[mi][ni], 0, 0, 0);
  }
  __syncthreads();

  // ---- T = sigmoid(gl) * O (O^T float4 gather), swizzled frag scatter ----
#pragma unroll
  for (int mi = 0; mi < 4; ++mi) {
    f32x4 o4v[4];
#pragma unroll
    for (int ni = 0; ni < 4; ++ni)
      o4v[ni] = *(const f32x4*)(O_T + (size_t)(col + ni * 16) * 256 + r0 +
                                mi * 16 + g * 4);
#pragma unroll
    for (int ni = 0; ni < 4; ++ni) {
      const int c2 = col + ni * 16;
      const int kb2 = c2 >> 5, g2 = (c2 >> 3) & 3, b2 = c2 & 7;
#pragma unroll
      for (int reg = 0; reg < 4; ++reg) {
        const float tv = fast_sigmoid_mul(o4v[ni][reg], acc[mi][ni][reg]);
        const int u = (mi * 8 + kb2) * 64 + (g * 4 + reg) + g2 * 16;
        const int byte = ((u << 4) ^ (((u >> 4) & 3) << 4)) + b2 * 2;
        *(short*)((char*)A_lds + byte) = f2bf(tv);
      }
    }
  }
  __syncthreads();

#pragma unroll
  for (int ni = 0; ni < 4; ++ni) {
    const float bo = b_o[col + ni * 16];
#pragma unroll
    for (int mi = 0; mi < 4; ++mi) acc[mi][ni] = (f32x4){bo, bo, bo, bo};
  }
#pragma unroll
  for (int kb = 0; kb < 8; ++kb) {
    bf16x8 a[4], bb[4];
#pragma unroll
    for (int mi = 0; mi < 4; ++mi) {
      const int u = (mi * 8 + kb) * 64 + l;
      const int byte = (u << 4) ^ (g << 4);
      a[mi] = *(const bf16x8*)((char*)A_lds + byte);
    }
#pragma unroll
    for (int ni = 0; ni < 4; ++ni)
      bb[ni] = *(const bf16x8*)(woB + (((size_t)kb * 256 + col + ni * 16) * 4 + g) * 8);
#pragma unroll
    for (int mi = 0; mi < 4; ++mi)
#pragma unroll
      for (int ni = 0; ni < 4; ++ni)
        acc[mi][ni] = __builtin_amdgcn_mfma_f32_16x16x32_bf16(a[mi], bb[ni], acc[mi][ni], 0, 0, 0);
  }

#pragma unroll
  for (int mi = 0; mi < 4; ++mi)
#pragma unroll
    for (int ni = 0; ni < 4; ++ni)
#pragma unroll
      for (int reg = 0; reg < 4; ++reg) {
        const int row = mi * 16 + g * 4 + reg;
        out[(size_t)(p0 + row) * 256 + col + ni * 16] = acc[mi][ni][reg];
      }
}

extern "C" void kernel_launch(void* const* d_in, const int* in_sizes, int n_in,
                              void* d_out, int out_size, void* d_ws, size_t ws_size,
                              hipStream_t stream) {
  const float* mIn  = (const float*)d_in[0];
  const float* ln_g = (const float*)d_in[1];
  const float* ln_b = (const float*)d_in[2];
  const float* w_q  = (const float*)d_in[3];
  const float* w_k  = (const float*)d_in[4];
  const float* w_v  = (const float*)d_in[5];
  const float* w_g  = (const float*)d_in[6];
  const float* b_g  = (const float*)d_in[7];
  const float* w_o  = (const float*)d_in[8];
  const float* b_o  = (const float*)d_in[9];
  const int*   mask = (const int*)d_in[10];
  float* outp = (float*)d_out;

  float* ws = (float*)d_ws;
  const size_t NP = (size_t)S_DIM * R_DIM;      // 262144
  float* mu_ws   = ws;                          // NP
  float* rs_ws   = mu_ws + NP;                  // NP
  short* Kt      = (short*)(rs_ws + NP);        // 256*1024*32 shorts
  short* Vt      = Kt + (size_t)256 * 1024 * 32;
  float* pool_ws = (float*)(Vt + (size_t)256 * 1024 * 32);  // 65536
  float* D_ws    = pool_ws + 65536;             // 2048
  float* Q_ws    = D_ws + 2048;                 // 65536
  float* Npart   = Q_ws + 65536;                // 262144
  float* O_T     = Npart + 262144;              // 65536 (transposed [c][r])
  short* wgB     = (short*)(O_T + 65536);       // 65536 shorts
  short* woB     = wgB + 65536;                 // 65536 shorts
  short* wkvB    = woB + 65536;                 // 16384 shorts

  hipMemsetAsync(pool_ws, 0, (65536 + 2048) * sizeof(float), stream);

  k0_prep<<<72, 256, 0, stream>>>(w_g, w_o, w_k, w_v, wgB, woB, wkvB);
  k1_ln_kv<<<dim3(S_DIM / 64, R_DIM), 256, 0, stream>>>(
      mIn, ln_g, ln_b, wkvB, mask, mu_ws, rs_ws, Kt, Vt, pool_ws);
  k2_q<<<R_DIM, 256, 0, stream>>>(pool_ws, mask, w_q, Q_ws);
  k3eb<<<dim3(4, R_DIM), 256, 0, stream>>>(Kt, Vt, Q_ws, mask, Npart, D_ws);
  k3c_norm<<<R_DIM, 256, 0, stream>>>(Npart, D_ws, O_T);
  k4_mfma<<<dim3(S_DIM * R_DIM / 64), 256, 0, stream>>>(
      mIn, ln_g, ln_b, mu_ws, rs_ws, wgB, b_g, O_T, woB, b_o, outp);
}

// Round 17
// 350.243 us; speedup vs baseline: 1.0524x; 1.0524x over previous
//
#include <hip/hip_runtime.h>
#include <math.h>

#define S_DIM 1024
#define R_DIM 256
#define C_DIM 256
#define SCALE 0.17677669529663687f  // 1/sqrt(32)

typedef short bf16x8 __attribute__((ext_vector_type(8)));
typedef float f32x4 __attribute__((ext_vector_type(4)));

__device__ __forceinline__ float wred(float v) {
#pragma unroll
  for (int m = 32; m >= 1; m >>= 1) v += __shfl_xor(v, m, 64);
  return v;
}

__device__ __forceinline__ short f2bf(float f) {
  union { float f; unsigned u; } v;
  v.f = f;
  unsigned r = v.u + 0x7fffu + ((v.u >> 16) & 1u);  // RNE
  return (short)(r >> 16);
}

__device__ __forceinline__ float bf2f(short s) {
  union { unsigned u; float f; } v;
  v.u = ((unsigned)(unsigned short)s) << 16;
  return v.f;
}

__device__ __forceinline__ float fast_sigmoid_mul(float o, float gl) {
  return o * __builtin_amdgcn_rcpf(1.f + __expf(-gl));
}

// ---------------- K0: pre-swizzle weights into B-fragment bf16 layouts ----
__global__ __launch_bounds__(256)
void k0_prep(const float* __restrict__ w_g, const float* __restrict__ w_o,
             const float* __restrict__ w_k, const float* __restrict__ w_v,
             short* __restrict__ wgB, short* __restrict__ woB,
             short* __restrict__ wkvB) {
  const int id = blockIdx.x * 256 + threadIdx.x;  // 18432 ids
  if (id < 16384) {
    const int which = id >> 13;
    const int s = id & 8191;
    const int n = s & 255, g = (s >> 8) & 3, kb = s >> 10;
    const float* W = which ? w_o : w_g;
    short* Out = which ? woB : wgB;
#pragma unroll
    for (int j = 0; j < 8; ++j)
      Out[(((size_t)kb * 256 + n) * 4 + g) * 8 + j] =
          f2bf(W[(size_t)(kb * 32 + g * 8 + j) * 256 + n]);
  } else {
    const int s = id - 16384;  // 0..2047
    const int n = s & 63, g = (s >> 6) & 3, kb = s >> 8;
    const float* W = (n < 32) ? w_k : w_v;
    const int nn = n & 31;
#pragma unroll
    for (int j = 0; j < 8; ++j)
      wkvB[(((size_t)kb * 64 + n) * 4 + g) * 8 + j] =
          f2bf(W[(size_t)(kb * 32 + g * 8 + j) * 32 + nn]);
  }
}

// ---------------- K1: LN -> bf16 frag LDS -> MFMA K/V(bf16,T) + pool ------
// K/V stored bf16 transposed: Kt/Vt[r][s][32]
__global__ __launch_bounds__(256, 4)
void k1_ln_kv(const float* __restrict__ mIn, const float* __restrict__ ln_g,
              const float* __restrict__ ln_b, const short* __restrict__ wkvB,
              const int* __restrict__ mask,
              float* __restrict__ mu_ws, float* __restrict__ rs_ws,
              short* __restrict__ Kt, short* __restrict__ Vt,
              float* __restrict__ pool_ws) {
  __shared__ __align__(16) short A_lds[2048 * 8];  // 32 KB, frag-ordered X
  __shared__ float mask_s[64];
  __shared__ float4 poolp[4][64];                  // 4 KB
  const int r  = blockIdx.y;
  const int s0 = blockIdx.x * 64;
  const int t  = threadIdx.x;

  if (t < 64) mask_s[t] = mask[(s0 + t) * R_DIM + r] ? 1.f : 0.f;

  // ---- pass 1: LN stats (4-lane reduce) + bf16 frag write ----
  {
    const int rw = t >> 2;  // row 0..63
    const int q  = t & 3;   // col quarter
    const size_t p = (size_t)(s0 + rw) * R_DIM + r;
    const float* src = mIn + p * C_DIM + q * 64;
    float4 xv[16];
    float sum = 0.f, ssq = 0.f;
#pragma unroll
    for (int i = 0; i < 16; ++i) {
      xv[i] = *(const float4*)(src + i * 4);
      sum += xv[i].x + xv[i].y + xv[i].z + xv[i].w;
      ssq += xv[i].x * xv[i].x + xv[i].y * xv[i].y + xv[i].z * xv[i].z +
             xv[i].w * xv[i].w;
    }
    sum += __shfl_xor(sum, 1, 64); ssq += __shfl_xor(ssq, 1, 64);
    sum += __shfl_xor(sum, 2, 64); ssq += __shfl_xor(ssq, 2, 64);
    const float mu = sum * (1.f / 256.f);
    const float var = ssq * (1.f / 256.f) - mu * mu;
    const float rs = rsqrtf(var + 1e-5f);
    if (q == 0) { mu_ws[p] = mu; rs_ws[p] = rs; }

    const int gw = rw >> 4;
    const int lf0 = rw & 15;
#pragma unroll
    for (int kh = 0; kh < 2; ++kh) {
      const int kb = 2 * q + kh;
#pragma unroll
      for (int g = 0; g < 4; ++g) {
        const int lidx = kh * 32 + g * 8;
        const float4 a0 = xv[lidx >> 2], a1 = xv[(lidx >> 2) + 1];
        const float4 g0 = *(const float4*)(ln_g + kb * 32 + g * 8);
        const float4 g1 = *(const float4*)(ln_g + kb * 32 + g * 8 + 4);
        const float4 b0 = *(const float4*)(ln_b + kb * 32 + g * 8);
        const float4 b1 = *(const float4*)(ln_b + kb * 32 + g * 8 + 4);
        bf16x8 f;
        f[0] = f2bf((a0.x - mu) * rs * g0.x + b0.x);
        f[1] = f2bf((a0.y - mu) * rs * g0.y + b0.y);
        f[2] = f2bf((a0.z - mu) * rs * g0.z + b0.z);
        f[3] = f2bf((a0.w - mu) * rs * g0.w + b0.w);
        f[4] = f2bf((a1.x - mu) * rs * g1.x + b1.x);
        f[5] = f2bf((a1.y - mu) * rs * g1.y + b1.y);
        f[6] = f2bf((a1.z - mu) * rs * g1.z + b1.z);
        f[7] = f2bf((a1.w - mu) * rs * g1.w + b1.w);
        int byte = (((gw * 8 + kb) * 64 + lf0 + g * 16) << 4) ^ (((kb >> 1) & 3) << 5);
        *(bf16x8*)((char*)A_lds + byte) = f;
      }
    }
  }
  __syncthreads();

  // ---- MFMA: [16 rows/wave] x [64 cols K|V] x 256; store bf16 transposed --
  {
    const int w = t >> 6, l = t & 63;
    const int lm = l & 15, g = l >> 4;
    f32x4 acc[4];
#pragma unroll
    for (int ni = 0; ni < 4; ++ni) acc[ni] = (f32x4){0.f, 0.f, 0.f, 0.f};
#pragma unroll
    for (int kb = 0; kb < 8; ++kb) {
      const int byte = (((w * 8 + kb) * 64 + l) << 4) ^ (((kb >> 1) & 3) << 5);
      const bf16x8 a = *(const bf16x8*)((char*)A_lds + byte);
      bf16x8 bfr[4];
#pragma unroll
      for (int ni = 0; ni < 4; ++ni)
        bfr[ni] = *(const bf16x8*)(wkvB + (((size_t)kb * 64 + lm + ni * 16) * 4 + g) * 8);
#pragma unroll
      for (int ni = 0; ni < 4; ++ni)
        acc[ni] = __builtin_amdgcn_mfma_f32_16x16x32_bf16(a, bfr[ni], acc[ni], 0, 0, 0);
    }
#pragma unroll
    for (int ni = 0; ni < 4; ++ni) {
      const int col = lm + ni * 16;
      short* Out = (col < 32) ? Kt : Vt;
      const int cc = col & 31;
#pragma unroll
      for (int reg = 0; reg < 4; ++reg) {
        const int s = s0 + w * 16 + g * 4 + reg;
        Out[((size_t)r * 1024 + s) * 32 + cc] = f2bf(acc[ni][reg]);
      }
    }
  }

  // ---- pool: masked column sums from frag LDS (rotated rows) ----
  {
    const int lc = t & 63;
    const int wq = t >> 6;
    const int kb = lc >> 3, g2 = (lc >> 1) & 3, bh = (lc & 1) * 4;
    float4 ps = make_float4(0.f, 0.f, 0.f, 0.f);
    for (int i = 0; i < 16; ++i) {
      const int rloc = (i + lc) & 15;
      const int byte =
          ((((wq * 8 + kb) * 64 + rloc + g2 * 16) << 4) + bh * 2) ^ (((kb >> 1) & 3) << 5);
      const short4 xb = *(const short4*)((char*)A_lds + byte);
      const float mk = mask_s[wq * 16 + rloc];
      ps.x += mk * bf2f(xb.x);
      ps.y += mk * bf2f(xb.y);
      ps.z += mk * bf2f(xb.z);
      ps.w += mk * bf2f(xb.w);
    }
    poolp[wq][lc] = ps;
  }
  __syncthreads();
  if (t < 64) {
    const float4 a = poolp[0][t], b = poolp[1][t], c = poolp[2][t], d = poolp[3][t];
    atomicAdd(&pool_ws[r * C_DIM + t * 4 + 0], a.x + b.x + c.x + d.x);
    atomicAdd(&pool_ws[r * C_DIM + t * 4 + 1], a.y + b.y + c.y + d.y);
    atomicAdd(&pool_ws[r * C_DIM + t * 4 + 2], a.z + b.z + c.z + d.z);
    atomicAdd(&pool_ws[r * C_DIM + t * 4 + 3], a.w + b.w + c.w + d.w);
  }
}

// ---------------- K2: finalize pool, compute Q -----------------------------
__global__ __launch_bounds__(256, 2)
void k2_q(const float* __restrict__ pool_ws, const int* __restrict__ mask,
          const float* __restrict__ w_q, float* __restrict__ Q_ws) {
  __shared__ float qp[256];
  __shared__ float wsum[4];
  const int r = blockIdx.x, t = threadIdx.x;
  int cnt = 0;
  for (int s = t; s < S_DIM; s += 256) cnt += mask[s * R_DIM + r];
  float cf = wred((float)cnt);
  if ((t & 63) == 0) wsum[t >> 6] = cf;
  __syncthreads();
  const float denom = wsum[0] + wsum[1] + wsum[2] + wsum[3] + 1e-10f;
  qp[t] = pool_ws[r * C_DIM + t] / denom;
  __syncthreads();
  float acc = 0.f;
  for (int c = 0; c < 256; ++c) acc += qp[c] * w_q[c * 256 + t];
  Q_ws[r * 256 + t] = acc * SCALE;
}

// ---------------- K3eb: fused E=exp(QK) -> N_part, D_part -----------------
// grid (4, 256): block = 256-s chunk at one r. No E round-trip to HBM.
__global__ __launch_bounds__(256, 4)
void k3eb(const short* __restrict__ Kt, const short* __restrict__ Vt,
          const float* __restrict__ Q_ws, const int* __restrict__ mask,
          float* __restrict__ Npart, float* __restrict__ D_ws) {
  __shared__ float q[256];
  __shared__ float A_s[8 * 256];                   // 8 KB
  __shared__ __align__(16) short V_s[256 * 32];    // 16 KB
  const int ch = blockIdx.x, r = blockIdx.y;
  const int t = threadIdx.x;
  const int sb = ch * 256;

  q[t] = Q_ws[r * 256 + t];
  // stage V chunk (16 KB contiguous, linear)
  {
    const short* vp = Vt + ((size_t)r * 1024 + sb) * 32;
#pragma unroll
    for (int i = 0; i < 4; ++i) {
      const int u = i * 256 + t;
      *(bf16x8*)(V_s + u * 8) = *(const bf16x8*)(vp + u * 8);
    }
  }
  // K row for this thread's s
  const int s = sb + t;
  const short* kp = Kt + ((size_t)r * 1024 + s) * 32;
  bf16x8 kr[4];
#pragma unroll
  for (int i = 0; i < 4; ++i) kr[i] = *(const bf16x8*)(kp + i * 8);
  const int mk = mask[s * R_DIM + r];
  __syncthreads();

  float kf[32];
#pragma unroll
  for (int i = 0; i < 4; ++i)
#pragma unroll
    for (int j = 0; j < 8; ++j) kf[i * 8 + j] = bf2f(kr[i][j]);
#pragma unroll
  for (int h = 0; h < 8; ++h) {
    float a = 0.f;
#pragma unroll
    for (int d = 0; d < 32; ++d) a += q[h * 32 + d] * kf[d];
    A_s[h * 256 + t] = mk ? __expf(a) : 0.f;
  }
  __syncthreads();

  const int h = t >> 5, d = t & 31;
  const float* ap = A_s + h * 256;
  float o = 0.f;
  for (int s4 = 0; s4 < 256; s4 += 4) {
    const float4 a4 = *(const float4*)(ap + s4);
    o += a4.x * bf2f(V_s[(s4 + 0) * 32 + d]);
    o += a4.y * bf2f(V_s[(s4 + 1) * 32 + d]);
    o += a4.z * bf2f(V_s[(s4 + 2) * 32 + d]);
    o += a4.w * bf2f(V_s[(s4 + 3) * 32 + d]);
  }
  Npart[(size_t)ch * 65536 + r * 256 + t] = o;
  // D partial: strided sum within 32-lane d-group (xor<=16 stays in-group)
  float ds = 0.f;
  for (int s1 = d; s1 < 256; s1 += 32) ds += ap[s1];
#pragma unroll
  for (int mkk = 16; mkk >= 1; mkk >>= 1) ds += __shfl_xor(ds, mkk, 64);
  if (d == 0) atomicAdd(&D_ws[r * 8 + h], ds);
}

// ---------------- K3c: O = (sum_ch N) / D ---------------------------------
__global__ __launch_bounds__(256)
void k3c_norm(const float* __restrict__ Npart, const float* __restrict__ D_ws,
              float* __restrict__ O_ws) {
  const int r = blockIdx.x, t = threadIdx.x;
  const int idx = r * 256 + t;
  const float n = Npart[idx] + Npart[65536 + idx] + Npart[131072 + idx] +
                  Npart[196608 + idx];
  O_ws[idx] = n / (D_ws[r * 8 + (t >> 5)] + 1e-30f);
}

// ---------------- K4: recompute X -> gate GEMM -> sigmoid*O -> out GEMM ----
// (R6/R13 version — measured optimum across all k4 variants)
__global__ __launch_bounds__(256, 4)
void k4_mfma(const float* __restrict__ mIn, const float* __restrict__ ln_g,
             const float* __restrict__ ln_b, const float* __restrict__ mu_ws,
             const float* __restrict__ rs_ws, const short* __restrict__ wgB,
             const float* __restrict__ b_g, const float* __restrict__ O_ws,
             const short* __restrict__ woB, const float* __restrict__ b_o,
             float* __restrict__ out) {
  __shared__ __align__(16) short A_lds[2048 * 8];  // 32 KB
  const int t = threadIdx.x;
  const int p0 = blockIdx.x * 64;
  const int r0 = p0 & 255;
  const int l = t & 63;
  const int w = t >> 6;
  const int lm = l & 15;
  const int g = l >> 4;

  {
    const int row = w * 16 + lm;
    const size_t p = (size_t)(p0 + row);
    const float mu = mu_ws[p], rs = rs_ws[p];
    const float* mrow = mIn + p * 256 + g * 8;
    const float* gp = ln_g + g * 8;
    const float* bp = ln_b + g * 8;
#pragma unroll
    for (int kb = 0; kb < 8; ++kb) {
      const float4 m0 = *(const float4*)(mrow + kb * 32);
      const float4 m1 = *(const float4*)(mrow + kb * 32 + 4);
      const float4 g0 = *(const float4*)(gp + kb * 32);
      const float4 g1 = *(const float4*)(gp + kb * 32 + 4);
      const float4 b0 = *(const float4*)(bp + kb * 32);
      const float4 b1 = *(const float4*)(bp + kb * 32 + 4);
      bf16x8 xf;
      xf[0] = f2bf((m0.x - mu) * rs * g0.x + b0.x);
      xf[1] = f2bf((m0.y - mu) * rs * g0.y + b0.y);
      xf[2] = f2bf((m0.z - mu) * rs * g0.z + b0.z);
      xf[3] = f2bf((m0.w - mu) * rs * g0.w + b0.w);
      xf[4] = f2bf((m1.x - mu) * rs * g1.x + b1.x);
      xf[5] = f2bf((m1.y - mu) * rs * g1.y + b1.y);
      xf[6] = f2bf((m1.z - mu) * rs * g1.z + b1.z);
      xf[7] = f2bf((m1.w - mu) * rs * g1.w + b1.w);
      *(bf16x8*)(A_lds + ((w * 8 + kb) * 64 + l) * 8) = xf;
    }
  }
  __syncthreads();

  const int col = w * 64 + lm;
  f32x4 acc[4][4];

#pragma unroll
  for (int ni = 0; ni < 4; ++ni) {
    const float bg = b_g[col + ni * 16];
#pragma unroll
    for (int mi = 0; mi < 4; ++mi) acc[mi][ni] = (f32x4){bg, bg, bg, bg};
  }
#pragma unroll
  for (int kb = 0; kb < 8; ++kb) {
    bf16x8 a[4], bb[4];
#pragma unroll
    for (int mi = 0; mi < 4; ++mi)
      a[mi] = *(const bf16x8*)(A_lds + ((mi * 8 + kb) * 64 + l) * 8);
#pragma unroll
    for (int ni = 0; ni < 4; ++ni)
      bb[ni] = *(const bf16x8*)(wgB + (((size_t)kb * 256 + col + ni * 16) * 4 + g) * 8);
#pragma unroll
    for (int mi = 0; mi < 4; ++mi)
#pragma unroll
      for (int ni = 0; ni < 4; ++ni)
        acc[mi][ni] = __builtin_amdgcn_mfma_f32_16x16x32_bf16(a[mi], bb[ni], acc[mi][ni], 0, 0, 0);
  }
  __syncthreads();

#pragma unroll
  for (int mi = 0; mi < 4; ++mi) {
#pragma unroll
    for (int ni = 0; ni < 4; ++ni) {
      const int c2 = col + ni * 16;
      const int kb2 = c2 >> 5, g2 = (c2 >> 3) & 3, b2 = c2 & 7;
#pragma unroll
      for (int reg = 0; reg < 4; ++reg) {
        const int row = mi * 16 + g * 4 + reg;
        const float o = O_ws[(r0 + row) * 256 + c2];
        const float tv = fast_sigmoid_mul(o, acc[mi][ni][reg]);
        const int u = (mi * 8 + kb2) * 64 + (g * 4 + reg) + g2 * 16;
        const int byte = ((u << 4) ^ (((u >> 4) & 3) << 4)) + b2 * 2;
        *(short*)((char*)A_lds + byte) = f2bf(tv);
      }
    }
  }
  __syncthreads();

#pragma unroll
  for (int ni = 0; ni < 4; ++ni) {
    const float bo = b_o[col + ni * 16];
#pragma unroll
    for (int mi = 0; mi < 4; ++mi) acc[mi][ni] = (f32x4){bo, bo, bo, bo};
  }
#pragma unroll
  for (int kb = 0; kb < 8; ++kb) {
    bf16x8 a[4], bb[4];
#pragma unroll
    for (int mi = 0; mi < 4; ++mi) {
      const int u = (mi * 8 + kb) * 64 + l;
      const int byte = (u << 4) ^ (g << 4);
      a[mi] = *(const bf16x8*)((char*)A_lds + byte);
    }
#pragma unroll
    for (int ni = 0; ni < 4; ++ni)
      bb[ni] = *(const bf16x8*)(woB + (((size_t)kb * 256 + col + ni * 16) * 4 + g) * 8);
#pragma unroll
    for (int mi = 0; mi < 4; ++mi)
#pragma unroll
      for (int ni = 0; ni < 4; ++ni)
        acc[mi][ni] = __builtin_amdgcn_mfma_f32_16x16x32_bf16(a[mi], bb[ni], acc[mi][ni], 0, 0, 0);
  }

#pragma unroll
  for (int mi = 0; mi < 4; ++mi)
#pragma unroll
    for (int ni = 0; ni < 4; ++ni)
#pragma unroll
      for (int reg = 0; reg < 4; ++reg) {
        const int row = mi * 16 + g * 4 + reg;
        out[(size_t)(p0 + row) * 256 + col + ni * 16] = acc[mi][ni][reg];
      }
}

extern "C" void kernel_launch(void* const* d_in, const int* in_sizes, int n_in,
                              void* d_out, int out_size, void* d_ws, size_t ws_size,
                              hipStream_t stream) {
  const float* mIn  = (const float*)d_in[0];
  const float* ln_g = (const float*)d_in[1];
  const float* ln_b = (const float*)d_in[2];
  const float* w_q  = (const float*)d_in[3];
  const float* w_k  = (const float*)d_in[4];
  const float* w_v  = (const float*)d_in[5];
  const float* w_g  = (const float*)d_in[6];
  const float* b_g  = (const float*)d_in[7];
  const float* w_o  = (const float*)d_in[8];
  const float* b_o  = (const float*)d_in[9];
  const int*   mask = (const int*)d_in[10];
  float* outp = (float*)d_out;

  float* ws = (float*)d_ws;
  const size_t NP = (size_t)S_DIM * R_DIM;      // 262144
  float* mu_ws   = ws;                          // NP
  float* rs_ws   = mu_ws + NP;                  // NP
  short* Kt      = (short*)(rs_ws + NP);        // 256*1024*32 shorts
  short* Vt      = Kt + (size_t)256 * 1024 * 32;
  float* pool_ws = (float*)(Vt + (size_t)256 * 1024 * 32);  // 65536
  float* D_ws    = pool_ws + 65536;             // 2048
  float* Q_ws    = D_ws + 2048;                 // 65536
  float* Npart   = Q_ws + 65536;                // 262144
  float* O_ws    = Npart + 262144;              // 65536
  short* wgB     = (short*)(O_ws + 65536);      // 65536 shorts
  short* woB     = wgB + 65536;                 // 65536 shorts
  short* wkvB    = woB + 65536;                 // 16384 shorts

  hipMemsetAsync(pool_ws, 0, (65536 + 2048) * sizeof(float), stream);

  k0_prep<<<72, 256, 0, stream>>>(w_g, w_o, w_k, w_v, wgB, woB, wkvB);
  k1_ln_kv<<<dim3(S_DIM / 64, R_DIM), 256, 0, stream>>>(
      mIn, ln_g, ln_b, wkvB, mask, mu_ws, rs_ws, Kt, Vt, pool_ws);
  k2_q<<<R_DIM, 256, 0, stream>>>(pool_ws, mask, w_q, Q_ws);
  k3eb<<<dim3(4, R_DIM), 256, 0, stream>>>(Kt, Vt, Q_ws, mask, Npart, D_ws);
  k3c_norm<<<R_DIM, 256, 0, stream>>>(Npart, D_ws, O_ws);
  k4_mfma<<<dim3(S_DIM * R_DIM / 64), 256, 0, stream>>>(
      mIn, ln_g, ln_b, mu_ws, rs_ws, wgB, b_g, O_ws, woB, b_o, outp);
}